// Round 1
// baseline (280.525 us; speedup 1.0000x reference)
//
#include <hip/hip_runtime.h>

#define BN 1024      // B
#define EN 50000     // E
#define CN 512       // CLASS_NUM

// Native vector type (HIP's float4 is a struct; the nontemporal builtins
// require a real vector type).
typedef float v4f __attribute__((ext_vector_type(4)));

// ---------------------------------------------------------------------------
// Kernel 1: per-wave dot products.  (UNCHANGED from previous round — keeps
// the bench delta attributable to the bcast rewrite.)
//   waves [0, EN)     : parts[j]      = dot(tail[j, :], W2)
//   waves [EN, EN+BN) : parts[EN + i] = dot(hr[i, :],  W1) + b   (b folded)
// One wave (64 lanes) per 512-float row: each lane reads 2 v4f (fully
// coalesced, 16B/lane), then a 64-lane shuffle-tree reduction.
// ---------------------------------------------------------------------------
__global__ __launch_bounds__(256) void dots_kernel(
    const float* __restrict__ hr,
    const float* __restrict__ tail,
    const float* __restrict__ W,
    const float* __restrict__ bptr,
    float* __restrict__ parts,
    float* __restrict__ out)
{
    const int gtid = blockIdx.x * blockDim.x + threadIdx.x;
    const int wave = gtid >> 6;
    const int lane = threadIdx.x & 63;
    if (wave >= EN + BN) return;

    const v4f* r4;
    const v4f* w4;
    if (wave < EN) {
        r4 = (const v4f*)(tail + (size_t)wave * CN);
        w4 = (const v4f*)(W + CN);            // W2 = W[0, 512:1024]
    } else {
        r4 = (const v4f*)(hr + (size_t)(wave - EN) * CN);
        w4 = (const v4f*)W;                   // W1 = W[0, 0:512]
    }

    v4f a0 = __builtin_nontemporal_load(&r4[lane]);
    v4f a1 = __builtin_nontemporal_load(&r4[lane + 64]);
    v4f b0 = w4[lane];        // W: tiny, reused by all waves -> cached
    v4f b1 = w4[lane + 64];

    v4f p = a0 * b0 + a1 * b1;
    float sum = p.x + p.y + p.z + p.w;

    #pragma unroll
    for (int off = 32; off > 0; off >>= 1)
        sum += __shfl_down(sum, off, 64);

    if (lane == 0) {
        if (wave < EN) parts[wave] = sum;
        else           parts[wave] = sum + bptr[0];   // fold bias into hr_part
    }
    // Trailing tuple element (scalar 0) — written here, off the hot kernel.
    if (gtid == 0) out[(size_t)BN * EN] = 0.0f;
}

// ---------------------------------------------------------------------------
// Kernel 2 (REWRITTEN): scores[i, j] = hr_part[i] + tail_part[j].
// One block per output row: 1024 blocks x 512 threads = 4 blocks/CU x 8
// waves = 32 waves/CU (max occupancy).  Each thread loops over ~24 v4f
// chunks of its row (unroll 4 -> 4 loads + 4 stores in flight), REGULAR
// stores through L2 (the rocclr fill proves this path sustains 6.5 TB/s;
// the previous nontemporal path measured ~1.8 TB/s).  parts (200 KB) is
// the only live read data -> stays L2/L3-hot across its 1024x reuse.
// ---------------------------------------------------------------------------
__global__ __launch_bounds__(512) void bcast_kernel(
    const float* __restrict__ parts,
    float* __restrict__ out)
{
    const int i = blockIdx.x;
    const float hv = parts[EN + i];        // wave-uniform -> scalar load
    const v4f* t4 = (const v4f*)parts;
    v4f* orow = (v4f*)(out + (size_t)i * EN);

    // Row = EN/4 = 12500 v4f = 512*24 + 212.
    int j4 = threadIdx.x;
    #pragma unroll 4
    for (int it = 0; it < 24; ++it, j4 += 512) {
        orow[j4] = t4[j4] + hv;
    }
    if (j4 < EN / 4) {                     // remainder: first 212 threads
        orow[j4] = t4[j4] + hv;
    }
}

extern "C" void kernel_launch(void* const* d_in, const int* in_sizes, int n_in,
                              void* d_out, int out_size, void* d_ws, size_t ws_size,
                              hipStream_t stream)
{
    const float* hr   = (const float*)d_in[0];   // (1024, 512)
    const float* tail = (const float*)d_in[1];   // (50000, 512)
    const float* W    = (const float*)d_in[2];   // (1, 1024)
    const float* b    = (const float*)d_in[3];   // (1,)
    float* out = (float*)d_out;
    float* parts = (float*)d_ws;                 // EN + BN floats = 204 KB

    // Kernel 1: 51024 waves, 4 waves per 256-thread block.
    const int total_waves = EN + BN;
    const int blocks1 = (total_waves + 3) / 4;
    dots_kernel<<<blocks1, 256, 0, stream>>>(hr, tail, W, b, parts, out);

    // Kernel 2: one block per row, max-occupancy streaming broadcast add.
    bcast_kernel<<<BN, 512, 0, stream>>>(parts, out);
}